// Round 8
// baseline (87.017 us; speedup 1.0000x reference)
//
#include <hip/hip_runtime.h>
#include <math.h>

#define T_IN   2048
#define T_OUT  2276
#define NTH    512
#define CHUNK  5               // 512*5 = 2560 >= 2276
#define NWAVE  (NTH/64)
#define RATE   0.9f

typedef float v4f __attribute__((ext_vector_type(4)));

// LDS: three float planes [ur][ui][nr] (conflict-light b32 reads).
// Output staging ALIASES this region after the post-scan barrier.
#define NFR     2052           // frames 0..2048 used; padded to multiple of 4
#define ST_N    2304           // staging stride (>= T_OUT, 16B aligned)

// Flips the traversal-direction parity AFTER each main launch (stream-ordered,
// so every block within one launch sees a consistent value -> bijective row map).
__global__ void ts_flip_parity(unsigned* __restrict__ ws) { *ws ^= 1u; }

__global__ __launch_bounds__(NTH, 8)
void phase_vocoder_v8(const float* __restrict__ xr,
                      const float* __restrict__ xi,
                      float* __restrict__ out,
                      int n_rows, long long out_floats,
                      const unsigned* __restrict__ ws)
{
    __shared__ __align__(16) float smem[3 * NFR];
    __shared__ float2 wtot[NWAVE];
    float* ur  = smem;                 // unit-vector real, per input frame
    float* uim = smem + NFR;           // unit-vector imag
    float* nr  = smem + 2 * NFR;       // magnitude
    float* st_re = smem;               // aliases planes after the scan barrier
    float* st_im = smem + ST_N;

    // L3 sweep-thrash fix: alternate row order per launch. Any parity value
    // (even uninitialized workspace) gives a bijection -> always correct.
    const unsigned par = ws ? (*ws & 1u) : 0u;
    const int row  = par ? (n_rows - 1 - (int)blockIdx.x) : (int)blockIdx.x;
    const int tid  = threadIdx.x;
    const int lane = tid & 63;
    const int wid  = tid >> 6;

    // ---- Fill: unit vector + |s| per input frame (float4 loads, b128 LDS writes) ----
    {
        const float4 r = ((const float4*)(xr + (size_t)row * T_IN))[tid];
        const float4 m = ((const float4*)(xi + (size_t)row * T_IN))[tid];
        float urv[4], uiv[4], nn[4];
#pragma unroll
        for (int k = 0; k < 4; ++k) {
            float re = (&r.x)[k], im = (&m.x)[k];
            float a  = fmaf(re, re, im * im);
            float rs = __builtin_amdgcn_rsqf(a);
            bool  z  = !(a > 0.0f);            // angle(0)=0 -> unit (1,0), |s|=0
            nn[k]  = z ? 0.0f : a * rs;
            urv[k] = z ? 1.0f : re * rs;
            uiv[k] = z ? 0.0f : im * rs;
        }
        ((float4*)ur)[tid]  = make_float4(urv[0], urv[1], urv[2], urv[3]);
        ((float4*)uim)[tid] = make_float4(uiv[0], uiv[1], uiv[2], uiv[3]);
        ((float4*)nr)[tid]  = make_float4(nn[0],  nn[1],  nn[2],  nn[3]);
        if (tid == 0) {                        // zero-pad frame 2048
            ur[T_IN] = 1.0f; uim[T_IN] = 0.0f; nr[T_IN] = 0.0f;
        }
    }
    __syncthreads();

    // ---- Chunk: rotation c_t = unit(s[i0+1])*conj(unit(s[i0])), cum-product ----
    // ip caches i0(t-1); bit-identical to recomputing (int)((t-1)*RATE).
    const int   base  = tid * CHUNK;
    const float fbase = (float)base;           // exact: base < 2^24
    float cumr[CHUNK], cumi[CHUNK], mg[CHUNK];
    float rr = 1.0f, ri = 0.0f;
    int ip = (base > 0) ? (int)((fbase - 1.0f) * RATE) : 0;   // i0 of t-1
#pragma unroll
    for (int j = 0; j < CHUNK; ++j) {
        int t = base + j;
        float c_r = 1.0f, c_i = 0.0f, m = 0.0f;
        if (t < T_OUT) {
            float ts    = (fbase + (float)j) * RATE;   // == (float)t * RATE bitwise
            int   i0    = (int)ts;
            float alpha = ts - (float)i0;
            float n0 = nr[i0];
            float n1 = nr[i0 + 1];
            m = alpha * n1 + (1.0f - alpha) * n0;
            if (t == 0) {
                c_r = ur[0]; c_i = uim[0];
            } else {
                float bx = ur[ip],     by = uim[ip];       // frame i0(t-1)
                float ax = ur[ip + 1], ay = uim[ip + 1];
                c_r = fmaf(ax, bx,  ay * by);              // a * conj(b)
                c_i = fmaf(ay, bx, -ax * by);
            }
            ip = i0;
        }
        float tr = fmaf(rr, c_r, -ri * c_i);
        float ti = fmaf(rr, c_i,  ri * c_r);
        rr = tr; ri = ti;
        cumr[j] = rr; cumi[j] = ri; mg[j] = m;   // cum saved -> ILP epilogue
    }

    // renormalize thread total: bounds cross-thread magnitude drift
    {
        float s = __builtin_amdgcn_rsqf(fmaf(rr, rr, ri * ri));
        rr *= s; ri *= s;
    }

    // ---- wave-level inclusive scan (complex product, 6 shuffle steps) ----
#pragma unroll
    for (int off = 1; off < 64; off <<= 1) {
        float or_ = __shfl_up(rr, off);
        float oi_ = __shfl_up(ri, off);
        bool ok = (lane >= off);
        or_ = ok ? or_ : 1.0f;
        oi_ = ok ? oi_ : 0.0f;
        float tr = fmaf(or_, rr, -oi_ * ri);
        float ti = fmaf(or_, ri,  oi_ * rr);
        rr = tr; ri = ti;
    }
    // exclusive prefix within wave
    float er = __shfl_up(rr, 1);
    float ei = __shfl_up(ri, 1);
    if (lane == 0) { er = 1.0f; ei = 0.0f; }
    if (lane == 63) wtot[wid] = make_float2(rr, ri);
    __syncthreads();   // also closes all plane reads -> staging may alias now

    // ---- cross-wave exclusive prefix (uniform per wave) ----
    float pr = er, pi = ei;
#pragma unroll
    for (int w = 0; w < NWAVE; ++w) {
        if (w < wid) {
            float2 wt = wtot[w];
            float tr = fmaf(wt.x, pr, -wt.y * pi);
            float ti = fmaf(wt.x, pi,  wt.y * pr);
            pr = tr; pi = ti;
        }
    }

    // ---- epilogue: independent prefix-apply (no serial chain) -> staged re/im ----
#pragma unroll
    for (int j = 0; j < CHUNK; ++j) {
        int t = base + j;
        if (t < T_OUT) {
            float orr = fmaf(pr, cumr[j], -pi * cumi[j]);
            float oii = fmaf(pr, cumi[j],  pi * cumr[j]);
            st_re[t] = mg[j] * orr;
            st_im[t] = mg[j] * oii;
        }
    }
    __syncthreads();

    // ---- coalesced planar float4 store (nontemporal: bypass L3, keep it for input) ----
    const long long nplane = (long long)n_rows * T_OUT;
    const long long rowb   = (long long)row * T_OUT;
    const v4f* sre4 = (const v4f*)st_re;
    const v4f* sim4 = (const v4f*)st_im;
    for (int v = tid; v < T_OUT / 4; v += NTH) {
        long long o = rowb + 4 * (long long)v;
        if (o + 3 < out_floats)
            __builtin_nontemporal_store(sre4[v], (v4f*)(out + o));
        if (nplane + o + 3 < out_floats)
            __builtin_nontemporal_store(sim4[v], (v4f*)(out + nplane + o));
    }
}

extern "C" void kernel_launch(void* const* d_in, const int* in_sizes, int n_in,
                              void* d_out, int out_size, void* d_ws, size_t ws_size,
                              hipStream_t stream) {
    const float* xr = (const float*)d_in[0];
    const float* xi = (const float*)d_in[1];
    float* out = (float*)d_out;
    const int n_rows = in_sizes[0] / T_IN;     // 16 * 1025 = 16400
    unsigned* ws = (d_ws && ws_size >= sizeof(unsigned)) ? (unsigned*)d_ws : nullptr;
    phase_vocoder_v8<<<n_rows, NTH, 0, stream>>>(xr, xi, out, n_rows,
                                                 (long long)out_size, ws);
    if (ws) ts_flip_parity<<<1, 1, 0, stream>>>(ws);
}

// Round 9
// 85.914 us; speedup vs baseline: 1.0128x; 1.0128x over previous
//
#include <hip/hip_runtime.h>
#include <math.h>

#define T_IN   2048
#define T_OUT  2276
#define NTH    512
#define CHUNK  5               // 512*5 = 2560 >= 2276
#define NWAVE  (NTH/64)
#define RATE   0.9f

typedef float v4f __attribute__((ext_vector_type(4)));

// LDS: three float planes [ur][ui][nr] (conflict-light b32 reads).
// Output staging ALIASES this region after the post-scan barrier.
#define NFR     2052           // frames 0..2048 used; padded to multiple of 4
#define ST_N    2304           // staging stride (>= T_OUT, 16B aligned)

// NOTE (session journal): rounds 2-8 established this op is memory-streaming
// bound. True HBM traffic = 268 MB in + 299 MB out = 567 MB/iter (rocprof
// FETCH/WRITE on gfx950 read exactly half of both streams, incl. the cold
// pass -> 2x undercount, not cache reuse). 85.7 us == 6.6 TB/s effective,
// at the measured achievable ceiling. Compute-side variants (bank-conflict
// fix, VALU bookkeeping cuts, occupancy 43->78%) were all invariant at
// 86 +/- 1 us; L3 direction-alternation was neutral (FETCH unchanged).

__global__ __launch_bounds__(NTH, 8)
void phase_vocoder_v9(const float* __restrict__ xr,
                      const float* __restrict__ xi,
                      float* __restrict__ out,
                      int n_rows, long long out_floats)
{
    __shared__ __align__(16) float smem[3 * NFR];
    __shared__ float2 wtot[NWAVE];
    float* ur  = smem;                 // unit-vector real, per input frame
    float* uim = smem + NFR;           // unit-vector imag
    float* nr  = smem + 2 * NFR;       // magnitude
    float* st_re = smem;               // aliases planes after the scan barrier
    float* st_im = smem + ST_N;

    const int row  = blockIdx.x;
    const int tid  = threadIdx.x;
    const int lane = tid & 63;
    const int wid  = tid >> 6;

    // ---- Fill: unit vector + |s| per input frame (float4 loads, b128 LDS writes) ----
    {
        const float4 r = ((const float4*)(xr + (size_t)row * T_IN))[tid];
        const float4 m = ((const float4*)(xi + (size_t)row * T_IN))[tid];
        float urv[4], uiv[4], nn[4];
#pragma unroll
        for (int k = 0; k < 4; ++k) {
            float re = (&r.x)[k], im = (&m.x)[k];
            float a  = fmaf(re, re, im * im);
            float rs = __builtin_amdgcn_rsqf(a);
            bool  z  = !(a > 0.0f);            // angle(0)=0 -> unit (1,0), |s|=0
            nn[k]  = z ? 0.0f : a * rs;
            urv[k] = z ? 1.0f : re * rs;
            uiv[k] = z ? 0.0f : im * rs;
        }
        ((float4*)ur)[tid]  = make_float4(urv[0], urv[1], urv[2], urv[3]);
        ((float4*)uim)[tid] = make_float4(uiv[0], uiv[1], uiv[2], uiv[3]);
        ((float4*)nr)[tid]  = make_float4(nn[0],  nn[1],  nn[2],  nn[3]);
        if (tid == 0) {                        // zero-pad frame 2048
            ur[T_IN] = 1.0f; uim[T_IN] = 0.0f; nr[T_IN] = 0.0f;
        }
    }
    __syncthreads();

    // ---- Chunk: rotation c_t = unit(s[i0+1])*conj(unit(s[i0])), cum-product ----
    // ip caches i0(t-1); bit-identical to recomputing (int)((t-1)*RATE).
    const int   base  = tid * CHUNK;
    const float fbase = (float)base;           // exact: base < 2^24
    float cumr[CHUNK], cumi[CHUNK], mg[CHUNK];
    float rr = 1.0f, ri = 0.0f;
    int ip = (base > 0) ? (int)((fbase - 1.0f) * RATE) : 0;   // i0 of t-1
#pragma unroll
    for (int j = 0; j < CHUNK; ++j) {
        int t = base + j;
        float c_r = 1.0f, c_i = 0.0f, m = 0.0f;
        if (t < T_OUT) {
            float ts    = (fbase + (float)j) * RATE;   // == (float)t * RATE bitwise
            int   i0    = (int)ts;
            float alpha = ts - (float)i0;
            float n0 = nr[i0];
            float n1 = nr[i0 + 1];
            m = alpha * n1 + (1.0f - alpha) * n0;
            if (t == 0) {
                c_r = ur[0]; c_i = uim[0];
            } else {
                float bx = ur[ip],     by = uim[ip];       // frame i0(t-1)
                float ax = ur[ip + 1], ay = uim[ip + 1];
                c_r = fmaf(ax, bx,  ay * by);              // a * conj(b)
                c_i = fmaf(ay, bx, -ax * by);
            }
            ip = i0;
        }
        float tr = fmaf(rr, c_r, -ri * c_i);
        float ti = fmaf(rr, c_i,  ri * c_r);
        rr = tr; ri = ti;
        cumr[j] = rr; cumi[j] = ri; mg[j] = m;   // cum saved -> ILP epilogue
    }

    // renormalize thread total: bounds cross-thread magnitude drift
    {
        float s = __builtin_amdgcn_rsqf(fmaf(rr, rr, ri * ri));
        rr *= s; ri *= s;
    }

    // ---- wave-level inclusive scan (complex product, 6 shuffle steps) ----
#pragma unroll
    for (int off = 1; off < 64; off <<= 1) {
        float or_ = __shfl_up(rr, off);
        float oi_ = __shfl_up(ri, off);
        bool ok = (lane >= off);
        or_ = ok ? or_ : 1.0f;
        oi_ = ok ? oi_ : 0.0f;
        float tr = fmaf(or_, rr, -oi_ * ri);
        float ti = fmaf(or_, ri,  oi_ * rr);
        rr = tr; ri = ti;
    }
    // exclusive prefix within wave
    float er = __shfl_up(rr, 1);
    float ei = __shfl_up(ri, 1);
    if (lane == 0) { er = 1.0f; ei = 0.0f; }
    if (lane == 63) wtot[wid] = make_float2(rr, ri);
    __syncthreads();   // also closes all plane reads -> staging may alias now

    // ---- cross-wave exclusive prefix (uniform per wave) ----
    float pr = er, pi = ei;
#pragma unroll
    for (int w = 0; w < NWAVE; ++w) {
        if (w < wid) {
            float2 wt = wtot[w];
            float tr = fmaf(wt.x, pr, -wt.y * pi);
            float ti = fmaf(wt.x, pi,  wt.y * pr);
            pr = tr; pi = ti;
        }
    }

    // ---- epilogue: independent prefix-apply (no serial chain) -> staged re/im ----
#pragma unroll
    for (int j = 0; j < CHUNK; ++j) {
        int t = base + j;
        if (t < T_OUT) {
            float orr = fmaf(pr, cumr[j], -pi * cumi[j]);
            float oii = fmaf(pr, cumi[j],  pi * cumr[j]);
            st_re[t] = mg[j] * orr;
            st_im[t] = mg[j] * oii;
        }
    }
    __syncthreads();

    // ---- coalesced planar float4 store (nontemporal: output never re-read) ----
    const long long nplane = (long long)n_rows * T_OUT;
    const long long rowb   = (long long)row * T_OUT;
    const v4f* sre4 = (const v4f*)st_re;
    const v4f* sim4 = (const v4f*)st_im;
    for (int v = tid; v < T_OUT / 4; v += NTH) {
        long long o = rowb + 4 * (long long)v;
        if (o + 3 < out_floats)
            __builtin_nontemporal_store(sre4[v], (v4f*)(out + o));
        if (nplane + o + 3 < out_floats)
            __builtin_nontemporal_store(sim4[v], (v4f*)(out + nplane + o));
    }
}

extern "C" void kernel_launch(void* const* d_in, const int* in_sizes, int n_in,
                              void* d_out, int out_size, void* d_ws, size_t ws_size,
                              hipStream_t stream) {
    const float* xr = (const float*)d_in[0];
    const float* xi = (const float*)d_in[1];
    float* out = (float*)d_out;
    const int n_rows = in_sizes[0] / T_IN;     // 16 * 1025 = 16400
    phase_vocoder_v9<<<n_rows, NTH, 0, stream>>>(xr, xi, out, n_rows,
                                                 (long long)out_size);
}